// Round 10
// baseline (339.860 us; speedup 1.0000x reference)
//
#include <hip/hip_runtime.h>
#include <hip/hip_bf16.h>
#include <cstdint>
#include <cstddef>

typedef __attribute__((ext_vector_type(8))) __bf16 bf16x8;
typedef __attribute__((ext_vector_type(4))) float f32x4;
typedef __attribute__((ext_vector_type(16))) float f32x16;

#define MFMA16(a, b, c) __builtin_amdgcn_mfma_f32_16x16x32_bf16((a), (b), (c), 0, 0, 0)
#define MFMA32(a, b, c) __builtin_amdgcn_mfma_f32_32x32x16_bf16((a), (b), (c), 0, 0, 0)

__device__ __forceinline__ f32x16 zf16() {
    f32x16 z;
    #pragma unroll
    for (int r = 0; r < 16; ++r) z[r] = 0.f;
    return z;
}

__device__ __forceinline__ unsigned pk2(float lo, float hi) {
    unsigned w;
    asm("v_cvt_pk_bf16_f32 %0, %1, %2" : "=v"(w) : "v"(lo), "v"(hi));
    return w;
}
__device__ __forceinline__ void swap32(unsigned& a, unsigned& b) {
    asm("v_permlane32_swap_b32 %0, %1" : "+v"(a), "+v"(b));
}
__device__ __forceinline__ bf16x8 mkfrag(unsigned a, unsigned b, unsigned c, unsigned d) {
    union { unsigned u[4]; bf16x8 v; } x;
    x.u[0] = a; x.u[1] = b; x.u[2] = c; x.u[3] = d;
    return x.v;
}

// ---------------------------------------------------------------------------
// prep (fused): blocks 0..511 = x transpose+cvt; 512..639 = VO transpose;
// 640..895 = Q/K weight cvt (Q scaled by log2e/16).
// ---------------------------------------------------------------------------
__global__ __launch_bounds__(256) void prep(const float* __restrict__ x,
                                            const float* __restrict__ Qw,
                                            const float* __restrict__ Kw,
                                            const float* __restrict__ VO,
                                            __bf16* __restrict__ xT,
                                            __bf16* __restrict__ xrow,
                                            __bf16* __restrict__ wb,
                                            __bf16* __restrict__ vot) {
    __shared__ float tile[64][65];
    const int bid = blockIdx.x;
    if (bid < 512) {
        const int b = bid >> 8;
        const int rem = bid & 255;
        const int tt = rem >> 2, dd = rem & 3;
        const int t0 = tt * 64, d0 = dd * 64;
        #pragma unroll
        for (int j = 0; j < 16; ++j) {
            int idx = j * 256 + threadIdx.x;
            int t = idx >> 6, d = idx & 63;
            float v = x[((size_t)(b * 4096 + t0 + t)) * 256 + d0 + d];
            tile[t][d] = v;
            xrow[((size_t)(b * 4096 + t0 + t)) * 256 + d0 + d] = (__bf16)v;
        }
        __syncthreads();
        #pragma unroll
        for (int j = 0; j < 16; ++j) {
            int idx = j * 256 + threadIdx.x;
            int d = idx >> 6, t = idx & 63;
            xT[((size_t)(b * 256 + d0 + d)) * 4096 + t0 + t] = (__bf16)tile[t][d];
        }
    } else if (bid < 640) {
        const int k = bid - 512;
        const int h = k >> 4;
        const int rem = k & 15;
        const int dt = rem >> 2, et = rem & 3;
        const int d0 = dt * 64, e0 = et * 64;
        #pragma unroll
        for (int j = 0; j < 16; ++j) {
            int idx = j * 256 + threadIdx.x;
            int d = idx >> 6, e = idx & 63;
            tile[d][e] = VO[((size_t)(h * 256 + d0 + d)) * 256 + e0 + e];
        }
        __syncthreads();
        #pragma unroll
        for (int j = 0; j < 16; ++j) {
            int idx = j * 256 + threadIdx.x;
            int e = idx >> 6, d = idx & 63;
            vot[((size_t)(e0 + e)) * 2048 + h * 256 + d0 + d] = (__bf16)tile[d][e];
        }
    } else {
        const float cl = 1.4426950408889634f / 16.0f;
        #pragma unroll
        for (int e = 0; e < 2; ++e) {
            int i = (bid - 640) * 512 + e * 256 + threadIdx.x;
            float v = (i < 65536) ? Qw[i] * cl : Kw[i - 65536];
            wb[i] = (__bf16)v;
        }
    }
}

// ---------------------------------------------------------------------------
// proj: block = 64 t-rows (4 waves x 16 rows); wave keeps its 16-row x
// A-fragments in registers and loops all 16 (h,s) tasks (weights bf16).
// ---------------------------------------------------------------------------
__global__ __launch_bounds__(256) void proj_kernel(const __bf16* __restrict__ xrow,
                                                   const __bf16* __restrict__ wb,
                                                   __bf16* __restrict__ qo,
                                                   __bf16* __restrict__ ko) {
    const int w = threadIdx.x >> 6;
    const int l = threadIdx.x & 63;
    const int g = l >> 4, c = l & 15;
    const int tg = blockIdx.x * 64 + w * 16;

    bf16x8 af[8];
    #pragma unroll
    for (int kk = 0; kk < 8; ++kk)
        af[kk] = *(const bf16x8*)(xrow + (size_t)(tg + c) * 256 + kk * 32 + g * 8);

    const int b = tg >> 12, t = tg & 4095;
    #pragma unroll
    for (int hs = 0; hs < 16; ++hs) {
        const int h = hs >> 1, s = hs & 1;
        const __bf16* W = wb + (size_t)(s * 8 + h) * 8192;  // [32][256]
        f32x4 acc0 = {0.f, 0.f, 0.f, 0.f}, acc1 = {0.f, 0.f, 0.f, 0.f};
        #pragma unroll
        for (int kk = 0; kk < 8; ++kk) {
            bf16x8 b0 = *(const bf16x8*)(W + (size_t)c * 256 + kk * 32 + g * 8);
            bf16x8 b1 = *(const bf16x8*)(W + (size_t)(16 + c) * 256 + kk * 32 + g * 8);
            acc0 = MFMA16(af[kk], b0, acc0);
            acc1 = MFMA16(af[kk], b1, acc1);
        }
        __bf16* outp = s ? ko : qo;
        const size_t obase = (size_t)(b * 8 + h) * 4096 + t;
        #pragma unroll
        for (int i = 0; i < 4; ++i) {
            outp[(obase + 4 * g + i) * 32 + c]      = (__bf16)acc0[i];
            outp[(obase + 4 * g + i) * 32 + 16 + c] = (__bf16)acc1[i];
        }
    }
}

// ---------------------------------------------------------------------------
// attn v10: v9 d-split (wave = 64q x 128d; LDS reads halved) with SEQUENTIAL
// per-q-half softmax so only one score-pair is live at a time -> fits the
// 256 VGPR+AGPR per-wave budget of a 512-thread block (2 waves/SIMD).
// No-max softmax; counted vmcnt(4) barrier; setprio around PV.
// grid = 256 blocks x 512 threads (1 block/CU)
// ---------------------------------------------------------------------------
__device__ __forceinline__ void stage_x(const __bf16* __restrict__ xTg_b,
                                        unsigned char* xbuf, int u0, int tid) {
    #pragma unroll
    for (int j = 0; j < 4; ++j) {
        int ch = j * 512 + tid;
        int d = ch >> 3;
        int slog = (ch & 7) ^ (d & 7);
        const __bf16* src = xTg_b + (size_t)d * 4096 + u0 + slog * 8;
        unsigned char* dst = xbuf + (size_t)(j * 512 + (tid & ~63)) * 16;  // wave-uniform
        __builtin_amdgcn_global_load_lds(
            (const __attribute__((address_space(1))) unsigned int*)src,
            (__attribute__((address_space(3))) unsigned int*)dst, 16, 0, 0);
    }
}

#define MKFRAG(dst, V, base)                                   \
    {                                                          \
        unsigned wa = pk2(V[(base) + 0], V[(base) + 1]);       \
        unsigned wb_ = pk2(V[(base) + 2], V[(base) + 3]);      \
        unsigned wc = pk2(V[(base) + 4], V[(base) + 5]);       \
        unsigned wd = pk2(V[(base) + 6], V[(base) + 7]);       \
        swap32(wa, wc);                                        \
        swap32(wb_, wd);                                       \
        dst = mkfrag(wa, wb_, wc, wd);                         \
    }

__global__ __launch_bounds__(512, 2) void attn_kernel(const __bf16* __restrict__ qg,
                                                      const __bf16* __restrict__ kg,
                                                      const __bf16* __restrict__ xTg,
                                                      __bf16* __restrict__ ctx) {
    __shared__ __align__(16) unsigned char lds[65536 + 2048];
    unsigned char* xbuf0 = lds;
    unsigned char* xbuf1 = lds + 32768;

    const int bid = blockIdx.x;
    const int bh = bid >> 4;
    const int tt = bid & 15;
    const int b = bh >> 3, h = bh & 7;
    const int t0 = tt * 256;
    const int tid = threadIdx.x;
    const int w = tid >> 6;
    const int qgi = w >> 1;          // q-group 0..3 (64 rows each)
    const int dh = w & 1;            // d-half 0..1 (128 cols each)
    const int l = tid & 63;
    const int l31 = l & 31, hi = l >> 5;

    float* scale_w = (float*)(lds + 65536) + w * 64;

    const __bf16* xTg_b = xTg + (size_t)b * 256 * 4096;
    const __bf16* kg_bh = kg + (size_t)bh * 4096 * 32;

    // Q B-fragments: qf[qh][st] for q = t0 + qgi*64 + qh*32 + l31
    bf16x8 qf[2][2];
    #pragma unroll
    for (int qh = 0; qh < 2; ++qh) {
        const size_t qoff = ((size_t)bh * 4096 + t0 + qgi * 64 + qh * 32 + l31) * 32;
        qf[qh][0] = *(const bf16x8*)(qg + qoff + hi * 8);
        qf[qh][1] = *(const bf16x8*)(qg + qoff + 16 + hi * 8);
    }

    f32x16 acc[2][4];
    #pragma unroll
    for (int qh = 0; qh < 2; ++qh)
        #pragma unroll
        for (int n = 0; n < 4; ++n)
            acc[qh][n] = zf16();

    float lsum0 = 0.f, lsum1 = 0.f;
    const int swz = (l31 & 7) << 4;

    bf16x8 kA[2][2];
    #pragma unroll
    for (int s = 0; s < 2; ++s)
        #pragma unroll
        for (int st = 0; st < 2; ++st)
            kA[s][st] = *(const bf16x8*)(kg_bh + (size_t)(s * 32 + l31) * 32 + st * 16 + hi * 8);

    stage_x(xTg_b, xbuf0, 0, tid);
    __syncthreads();

    for (int ut = 0; ut < 64; ++ut) {
        unsigned char* xcur = (ut & 1) ? xbuf1 : xbuf0;
        unsigned char* xnxt = (ut & 1) ? xbuf0 : xbuf1;
        if (ut < 63) stage_x(xTg_b, xnxt, (ut + 1) * 64, tid);

        bf16x8 pf0[4], pf1[4];

        // ---- q-half 0: QK -> exp2 -> pack (score regs die before half 1) ----
        {
            f32x16 s0 = MFMA32(kA[0][0], qf[0][0], zf16());
            s0 = MFMA32(kA[0][1], qf[0][1], s0);
            f32x16 s1 = MFMA32(kA[1][0], qf[0][0], zf16());
            s1 = MFMA32(kA[1][1], qf[0][1], s1);
            float rs = 0.f;
            #pragma unroll
            for (int r = 0; r < 16; ++r) {
                float p;
                p = __builtin_amdgcn_exp2f(s0[r]); s0[r] = p; rs += p;
                p = __builtin_amdgcn_exp2f(s1[r]); s1[r] = p; rs += p;
            }
            lsum0 += rs;
            MKFRAG(pf0[0], s0, 0);
            MKFRAG(pf0[1], s0, 8);
            MKFRAG(pf0[2], s1, 0);
            MKFRAG(pf0[3], s1, 8);
        }
        // ---- q-half 1 ----
        {
            f32x16 s0 = MFMA32(kA[0][0], qf[1][0], zf16());
            s0 = MFMA32(kA[0][1], qf[1][1], s0);
            f32x16 s1 = MFMA32(kA[1][0], qf[1][0], zf16());
            s1 = MFMA32(kA[1][1], qf[1][1], s1);
            float rs = 0.f;
            #pragma unroll
            for (int r = 0; r < 16; ++r) {
                float p;
                p = __builtin_amdgcn_exp2f(s0[r]); s0[r] = p; rs += p;
                p = __builtin_amdgcn_exp2f(s1[r]); s1[r] = p; rs += p;
            }
            lsum1 += rs;
            MKFRAG(pf1[0], s0, 0);
            MKFRAG(pf1[1], s0, 8);
            MKFRAG(pf1[2], s1, 0);
            MKFRAG(pf1[3], s1, 8);
        }

        if (ut < 63) {  // prefetch next k-tile fragments (after both QK uses)
            const __bf16* kp = kg_bh + (size_t)(ut + 1) * 64 * 32;
            #pragma unroll
            for (int s = 0; s < 2; ++s)
                #pragma unroll
                for (int st = 0; st < 2; ++st)
                    kA[s][st] = *(const bf16x8*)(kp + (size_t)(s * 32 + l31) * 32 + st * 16 + hi * 8);
        }

        // ---- PV: each xb feeds both q-halves (16 b128 reads, 32 MFMA) ----
        __builtin_amdgcn_s_setprio(1);
        #pragma unroll
        for (int kk = 0; kk < 4; ++kk) {
            #pragma unroll
            for (int n = 0; n < 4; ++n) {
                const bf16x8 xb = *(const bf16x8*)(xcur +
                    (dh * 128 + n * 32 + l31) * 128 + ((kk * 32 + hi * 16) ^ swz));
                acc[0][n] = MFMA32(pf0[kk], xb, acc[0][n]);
                acc[1][n] = MFMA32(pf1[kk], xb, acc[1][n]);
            }
        }
        __builtin_amdgcn_s_setprio(0);

        // counted barrier: drain the 4 stage loads, keep kA prefetch in flight
        asm volatile("s_waitcnt vmcnt(4)" ::: "memory");
        __builtin_amdgcn_s_barrier();
    }

    // ---- epilogue: combine lsum halves, broadcast 1/lsum by q-row ----
    lsum0 += __shfl_xor(lsum0, 32);
    lsum1 += __shfl_xor(lsum1, 32);
    if (!hi) {
        scale_w[l31]      = 1.0f / lsum0;
        scale_w[32 + l31] = 1.0f / lsum1;
    }
    #pragma unroll
    for (int qh = 0; qh < 2; ++qh) {
        f32x4 iv[4];
        #pragma unroll
        for (int q4 = 0; q4 < 4; ++q4)
            iv[q4] = *(const f32x4*)&scale_w[qh * 32 + q4 * 8 + hi * 4];
        #pragma unroll
        for (int n = 0; n < 4; ++n) {
            #pragma unroll
            for (int r = 0; r < 16; ++r) {
                int t = t0 + qgi * 64 + qh * 32 + (r & 3) + 8 * (r >> 2) + 4 * hi;
                int d = dh * 128 + n * 32 + l31;
                ctx[((size_t)(b * 4096 + t) * 8 + h) * 256 + d] =
                    (__bf16)(acc[qh][n][r] * iv[r >> 2][r & 3]);
            }
        }
    }
}

// ---------------------------------------------------------------------------
// gemm_out: out[bt][e] = sum_k ctx[bt][k] * VOT[e][k]; M=8192 K=2048 N=256.
// block = 64 m-rows x 128 e (4 waves; wave = 2 m-tiles x 32 e).
// ---------------------------------------------------------------------------
__global__ __launch_bounds__(256) void gemm_out(const __bf16* __restrict__ ctx,
                                                const __bf16* __restrict__ vot,
                                                float* __restrict__ out) {
    const int bid = blockIdx.x;
    const int mt2 = bid >> 1;
    const int eh = bid & 1;
    const int w = threadIdx.x >> 6;
    const int l = threadIdx.x & 63;
    const int l31 = l & 31, hi = l >> 5;
    const size_t a0row = (size_t)(mt2 * 64 + l31) * 2048;
    const size_t a1row = (size_t)(mt2 * 64 + 32 + l31) * 2048;
    const size_t brow  = (size_t)(eh * 128 + w * 32 + l31) * 2048;
    f32x16 acc0 = zf16(), acc1 = zf16();
    #pragma unroll 4
    for (int kk = 0; kk < 128; ++kk) {
        bf16x8 bfr = *(const bf16x8*)(vot + brow + kk * 16 + hi * 8);
        bf16x8 a0  = *(const bf16x8*)(ctx + a0row + kk * 16 + hi * 8);
        bf16x8 a1  = *(const bf16x8*)(ctx + a1row + kk * 16 + hi * 8);
        acc0 = MFMA32(a0, bfr, acc0);
        acc1 = MFMA32(a1, bfr, acc1);
    }
    const int e = eh * 128 + w * 32 + l31;
    #pragma unroll
    for (int r = 0; r < 16; ++r) {
        int crow = (r & 3) + 8 * (r >> 2) + 4 * hi;
        out[(size_t)(mt2 * 64 + crow) * 256 + e]      = acc0[r];
        out[(size_t)(mt2 * 64 + 32 + crow) * 256 + e] = acc1[r];
    }
}

// ---------------------------------------------------------------------------
extern "C" void kernel_launch(void* const* d_in, const int* in_sizes, int n_in,
                              void* d_out, int out_size, void* d_ws, size_t ws_size,
                              hipStream_t stream) {
    const float* x  = (const float*)d_in[0];  // [2][4096][256]
    const float* Qw = (const float*)d_in[1];  // [8][32][256]
    const float* Kw = (const float*)d_in[2];  // [8][32][256]
    const float* VO = (const float*)d_in[3];  // [8][256][256]
    float* out = (float*)d_out;               // [2][4096][256]

    char* ws = (char*)d_ws;
    __bf16* xT   = (__bf16*)(ws);                          // 4 MB  [2][256][4096]
    __bf16* xrow = (__bf16*)(ws + ((size_t)4 << 20));      // 4 MB  [2][4096][256]
    __bf16* qb   = (__bf16*)(ws + ((size_t)8 << 20));      // 4 MB  [2][8][4096][32]
    __bf16* kb   = (__bf16*)(ws + ((size_t)12 << 20));     // 4 MB
    __bf16* wb   = (__bf16*)(ws + ((size_t)16 << 20));     // 256 KB [2][8][32][256]
    __bf16* vot  = (__bf16*)(ws + ((size_t)17 << 20));     // 1 MB  [256][2048]
    __bf16* ctx  = (__bf16*)(ws + ((size_t)18 << 20));     // 32 MB [2][4096][8][256]

    prep<<<896, 256, 0, stream>>>(x, Qw, Kw, VO, xT, xrow, wb, vot);
    proj_kernel<<<128, 256, 0, stream>>>(xrow, wb, qb, kb);
    attn_kernel<<<256, 512, 0, stream>>>(qb, kb, xT, ctx);
    gemm_out<<<256, 256, 0, stream>>>(ctx, vot, out);
}

// Round 11
// 293.347 us; speedup vs baseline: 1.1586x; 1.1586x over previous
//
#include <hip/hip_runtime.h>
#include <hip/hip_bf16.h>
#include <cstdint>
#include <cstddef>

typedef __attribute__((ext_vector_type(8))) __bf16 bf16x8;
typedef __attribute__((ext_vector_type(4))) float f32x4;
typedef __attribute__((ext_vector_type(16))) float f32x16;

#define MFMA16(a, b, c) __builtin_amdgcn_mfma_f32_16x16x32_bf16((a), (b), (c), 0, 0, 0)
#define MFMA32(a, b, c) __builtin_amdgcn_mfma_f32_32x32x16_bf16((a), (b), (c), 0, 0, 0)

__device__ __forceinline__ f32x16 zf16() {
    f32x16 z;
    #pragma unroll
    for (int r = 0; r < 16; ++r) z[r] = 0.f;
    return z;
}

__device__ __forceinline__ unsigned pk2(float lo, float hi) {
    unsigned w;
    asm("v_cvt_pk_bf16_f32 %0, %1, %2" : "=v"(w) : "v"(lo), "v"(hi));
    return w;
}
__device__ __forceinline__ void swap32(unsigned& a, unsigned& b) {
    asm("v_permlane32_swap_b32 %0, %1" : "+v"(a), "+v"(b));
}
__device__ __forceinline__ bf16x8 mkfrag(unsigned a, unsigned b, unsigned c, unsigned d) {
    union { unsigned u[4]; bf16x8 v; } x;
    x.u[0] = a; x.u[1] = b; x.u[2] = c; x.u[3] = d;
    return x.v;
}

__device__ __forceinline__ bf16x8 cvt8(const float* __restrict__ p) {
    const float4 a = *(const float4*)p;
    const float4 b = *(const float4*)(p + 4);
    bf16x8 r;
    r[0] = (__bf16)a.x; r[1] = (__bf16)a.y; r[2] = (__bf16)a.z; r[3] = (__bf16)a.w;
    r[4] = (__bf16)b.x; r[5] = (__bf16)b.y; r[6] = (__bf16)b.z; r[7] = (__bf16)b.w;
    return r;
}
__device__ __forceinline__ bf16x8 cvt8s(const float* __restrict__ p, float s) {
    const float4 a = *(const float4*)p;
    const float4 b = *(const float4*)(p + 4);
    bf16x8 r;
    r[0] = (__bf16)(a.x * s); r[1] = (__bf16)(a.y * s);
    r[2] = (__bf16)(a.z * s); r[3] = (__bf16)(a.w * s);
    r[4] = (__bf16)(b.x * s); r[5] = (__bf16)(b.y * s);
    r[6] = (__bf16)(b.z * s); r[7] = (__bf16)(b.w * s);
    return r;
}

// ---------------------------------------------------------------------------
// prep (fused, all block-ranges independent):
//   blocks   0..511 : x [2][4096][256] fp32 -> xT [2][256][4096] bf16
//   blocks 512..639 : VO fp32 -> VOT bf16, VOT[e][h*256+d] = VO[h][d][e]
//   blocks 640..767 : proj — q,k = x·{Q,K}^T directly from fp32 inputs
//                     (Q scaled by log2e/16); block = 64 t-rows, 4 waves.
// ---------------------------------------------------------------------------
__global__ __launch_bounds__(256) void prep(const float* __restrict__ x,
                                            const float* __restrict__ Qw,
                                            const float* __restrict__ Kw,
                                            const float* __restrict__ VO,
                                            __bf16* __restrict__ xT,
                                            __bf16* __restrict__ vot,
                                            __bf16* __restrict__ qo,
                                            __bf16* __restrict__ ko) {
    __shared__ float tile[64][65];
    const int bid = blockIdx.x;
    if (bid < 512) {
        const int b = bid >> 8;
        const int rem = bid & 255;
        const int tt = rem >> 2, dd = rem & 3;
        const int t0 = tt * 64, d0 = dd * 64;
        #pragma unroll
        for (int j = 0; j < 16; ++j) {
            int idx = j * 256 + threadIdx.x;
            int t = idx >> 6, d = idx & 63;
            tile[t][d] = x[((size_t)(b * 4096 + t0 + t)) * 256 + d0 + d];
        }
        __syncthreads();
        #pragma unroll
        for (int j = 0; j < 16; ++j) {
            int idx = j * 256 + threadIdx.x;
            int d = idx >> 6, t = idx & 63;
            xT[((size_t)(b * 256 + d0 + d)) * 4096 + t0 + t] = (__bf16)tile[t][d];
        }
    } else if (bid < 640) {
        const int k = bid - 512;
        const int h = k >> 4;
        const int rem = k & 15;
        const int dt = rem >> 2, et = rem & 3;
        const int d0 = dt * 64, e0 = et * 64;
        #pragma unroll
        for (int j = 0; j < 16; ++j) {
            int idx = j * 256 + threadIdx.x;
            int d = idx >> 6, e = idx & 63;
            tile[d][e] = VO[((size_t)(h * 256 + d0 + d)) * 256 + e0 + e];
        }
        __syncthreads();
        #pragma unroll
        for (int j = 0; j < 16; ++j) {
            int idx = j * 256 + threadIdx.x;
            int e = idx >> 6, d = idx & 63;
            vot[((size_t)(e0 + e)) * 2048 + h * 256 + d0 + d] = (__bf16)tile[d][e];
        }
    } else {
        // ---- proj: independent of the other ranges (reads fp32 inputs) ----
        const int pb = bid - 640;            // 0..127
        const int w = threadIdx.x >> 6;
        const int l = threadIdx.x & 63;
        const int g = l >> 4, c = l & 15;
        const int tg = pb * 64 + w * 16;

        bf16x8 af[8];
        #pragma unroll
        for (int kk = 0; kk < 8; ++kk)
            af[kk] = cvt8(&x[(size_t)(tg + c) * 256 + kk * 32 + g * 8]);

        const int b = tg >> 12, t = tg & 4095;
        const float cl = 1.4426950408889634f / 16.0f;  // log2e/sqrt(D)
        #pragma unroll
        for (int hs = 0; hs < 16; ++hs) {
            const int h = hs >> 1, s = hs & 1;
            const float* W = (s ? Kw : Qw) + (size_t)h * 8192;  // [32][256] fp32
            const float ws = s ? 1.0f : cl;
            f32x4 acc0 = {0.f, 0.f, 0.f, 0.f}, acc1 = {0.f, 0.f, 0.f, 0.f};
            #pragma unroll
            for (int kk = 0; kk < 8; ++kk) {
                bf16x8 b0 = cvt8s(&W[(size_t)c * 256 + kk * 32 + g * 8], ws);
                bf16x8 b1 = cvt8s(&W[(size_t)(16 + c) * 256 + kk * 32 + g * 8], ws);
                acc0 = MFMA16(af[kk], b0, acc0);
                acc1 = MFMA16(af[kk], b1, acc1);
            }
            __bf16* outp = s ? ko : qo;
            const size_t obase = (size_t)(b * 8 + h) * 4096 + t;
            #pragma unroll
            for (int i = 0; i < 4; ++i) {
                outp[(obase + 4 * g + i) * 32 + c]      = (__bf16)acc0[i];
                outp[(obase + 4 * g + i) * 32 + 16 + c] = (__bf16)acc1[i];
            }
        }
    }
}

// ---------------------------------------------------------------------------
// attn v8 (known-good, byte-for-byte): 8 waves, 256 q-rows/block, grid 256.
// Wave owns 32 q-rows; swapped QK^T; no-max softmax (scores bounded);
// P via cvt_pk+permlane32_swap; x-tile double-buffered via global_load_lds;
// counted vmcnt(4) barrier; setprio around PV.
// ---------------------------------------------------------------------------
__device__ __forceinline__ void stage_x(const __bf16* __restrict__ xTg_b,
                                        unsigned char* xbuf, int u0, int tid) {
    #pragma unroll
    for (int j = 0; j < 4; ++j) {
        int ch = j * 512 + tid;
        int d = ch >> 3;
        int slog = (ch & 7) ^ (d & 7);
        const __bf16* src = xTg_b + (size_t)d * 4096 + u0 + slog * 8;
        unsigned char* dst = xbuf + (size_t)(j * 512 + (tid & ~63)) * 16;  // wave-uniform
        __builtin_amdgcn_global_load_lds(
            (const __attribute__((address_space(1))) unsigned int*)src,
            (__attribute__((address_space(3))) unsigned int*)dst, 16, 0, 0);
    }
}

#define MKFRAG(dst, V, base)                                   \
    {                                                          \
        unsigned wa = pk2(V[(base) + 0], V[(base) + 1]);       \
        unsigned wb_ = pk2(V[(base) + 2], V[(base) + 3]);      \
        unsigned wc = pk2(V[(base) + 4], V[(base) + 5]);       \
        unsigned wd = pk2(V[(base) + 6], V[(base) + 7]);       \
        swap32(wa, wc);                                        \
        swap32(wb_, wd);                                       \
        dst = mkfrag(wa, wb_, wc, wd);                         \
    }

__global__ __launch_bounds__(512, 2) void attn_kernel(const __bf16* __restrict__ qg,
                                                      const __bf16* __restrict__ kg,
                                                      const __bf16* __restrict__ xTg,
                                                      __bf16* __restrict__ ctx) {
    __shared__ __align__(16) unsigned char lds[65536 + 1024];
    unsigned char* xbuf0 = lds;
    unsigned char* xbuf1 = lds + 32768;

    const int bid = blockIdx.x;
    const int bh = bid >> 4;
    const int tt = bid & 15;
    const int b = bh >> 3, h = bh & 7;
    const int t0 = tt * 256;
    const int tid = threadIdx.x;
    const int w = tid >> 6;
    const int l = tid & 63;
    const int l31 = l & 31, hi = l >> 5;

    float* scale_w = (float*)(lds + 65536) + w * 32;

    const __bf16* xTg_b = xTg + (size_t)b * 256 * 4096;
    const __bf16* kg_bh = kg + (size_t)bh * 4096 * 32;

    const size_t qoff = ((size_t)bh * 4096 + t0 + w * 32 + l31) * 32;
    const bf16x8 qf0 = *(const bf16x8*)(qg + qoff + hi * 8);
    const bf16x8 qf1 = *(const bf16x8*)(qg + qoff + 16 + hi * 8);

    f32x16 acc[8];
    #pragma unroll
    for (int n = 0; n < 8; ++n)
        #pragma unroll
        for (int r = 0; r < 16; ++r) acc[n][r] = 0.f;

    float lsum = 0.f;               // per-lane partial; combined in epilogue
    const int swz = (l31 & 7) << 4;

    bf16x8 kA[2][2];
    #pragma unroll
    for (int s = 0; s < 2; ++s)
        #pragma unroll
        for (int st = 0; st < 2; ++st)
            kA[s][st] = *(const bf16x8*)(kg_bh + (size_t)(s * 32 + l31) * 32 + st * 16 + hi * 8);

    stage_x(xTg_b, xbuf0, 0, tid);
    __syncthreads();

    bf16x8 pf[4];
    for (int ut = 0; ut < 64; ++ut) {
        unsigned char* xcur = (ut & 1) ? xbuf1 : xbuf0;
        unsigned char* xnxt = (ut & 1) ? xbuf0 : xbuf1;
        if (ut < 63) stage_x(xTg_b, xnxt, (ut + 1) * 64, tid);

        // ---- S^T = K * Q^T (log2-domain, scale pre-folded into Q) ----
        f32x16 s0 = MFMA32(kA[0][0], qf0, zf16());
        s0 = MFMA32(kA[0][1], qf1, s0);
        f32x16 s1 = MFMA32(kA[1][0], qf0, zf16());
        s1 = MFMA32(kA[1][1], qf1, s1);

        if (ut < 63) {  // prefetch next k-tile fragments
            const __bf16* kp = kg_bh + (size_t)(ut + 1) * 64 * 32;
            #pragma unroll
            for (int s = 0; s < 2; ++s)
                #pragma unroll
                for (int st = 0; st < 2; ++st)
                    kA[s][st] = *(const bf16x8*)(kp + (size_t)(s * 32 + l31) * 32 + st * 16 + hi * 8);
        }

        // ---- P = exp2(S); no max subtraction (overflow-impossible range) ----
        float rs = 0.f;
        #pragma unroll
        for (int r = 0; r < 16; ++r) {
            float p = __builtin_amdgcn_exp2f(s0[r]);
            s0[r] = p; rs += p;
        }
        #pragma unroll
        for (int r = 0; r < 16; ++r) {
            float p = __builtin_amdgcn_exp2f(s1[r]);
            s1[r] = p; rs += p;
        }
        lsum += rs;

        bf16x8 pf0, pf1, pf2, pf3;
        MKFRAG(pf0, s0, 0);
        MKFRAG(pf1, s0, 8);
        MKFRAG(pf2, s1, 0);
        MKFRAG(pf3, s1, 8);
        pf[0] = pf0; pf[1] = pf1; pf[2] = pf2; pf[3] = pf3;

        // ---- PV: acc[n] += P[q][u] * x[u][d-tile n] ----
        __builtin_amdgcn_s_setprio(1);
        #pragma unroll
        for (int kk = 0; kk < 4; ++kk) {
            #pragma unroll
            for (int n = 0; n < 8; ++n) {
                const bf16x8 xb = *(const bf16x8*)(xcur + (n * 32 + l31) * 128 +
                                                   ((kk * 32 + hi * 16) ^ swz));
                acc[n] = MFMA32(pf[kk], xb, acc[n]);
            }
        }
        __builtin_amdgcn_s_setprio(0);

        // counted barrier: drain the 4 stage loads, keep kA prefetch in flight
        asm volatile("s_waitcnt vmcnt(4)" ::: "memory");
        __builtin_amdgcn_s_barrier();
    }

    // ---- epilogue: combine lsum across lane halves, broadcast 1/lsum ----
    lsum += __shfl_xor(lsum, 32);
    const float linv = 1.0f / lsum;
    if (!hi) scale_w[l31] = linv;
    f32x4 iv[4];
    #pragma unroll
    for (int q4 = 0; q4 < 4; ++q4)
        iv[q4] = *(const f32x4*)&scale_w[q4 * 8 + hi * 4];
    #pragma unroll
    for (int n = 0; n < 8; ++n) {
        #pragma unroll
        for (int r = 0; r < 16; ++r) {
            int t = t0 + w * 32 + (r & 3) + 8 * (r >> 2) + 4 * hi;
            int d = n * 32 + l31;
            ctx[((size_t)(b * 4096 + t) * 8 + h) * 256 + d] =
                (__bf16)(acc[n][r] * iv[r >> 2][r & 3]);
        }
    }
}

// ---------------------------------------------------------------------------
// gemm_out: out[bt][e] = sum_k ctx[bt][k] * VOT[e][k]; M=8192 K=2048 N=256.
// block = 64 m-rows x 128 e (4 waves; wave = 2 m-tiles x 32 e).
// ---------------------------------------------------------------------------
__global__ __launch_bounds__(256) void gemm_out(const __bf16* __restrict__ ctx,
                                                const __bf16* __restrict__ vot,
                                                float* __restrict__ out) {
    const int bid = blockIdx.x;
    const int mt2 = bid >> 1;
    const int eh = bid & 1;
    const int w = threadIdx.x >> 6;
    const int l = threadIdx.x & 63;
    const int l31 = l & 31, hi = l >> 5;
    const size_t a0row = (size_t)(mt2 * 64 + l31) * 2048;
    const size_t a1row = (size_t)(mt2 * 64 + 32 + l31) * 2048;
    const size_t brow  = (size_t)(eh * 128 + w * 32 + l31) * 2048;
    f32x16 acc0 = zf16(), acc1 = zf16();
    #pragma unroll 4
    for (int kk = 0; kk < 128; ++kk) {
        bf16x8 bfr = *(const bf16x8*)(vot + brow + kk * 16 + hi * 8);
        bf16x8 a0  = *(const bf16x8*)(ctx + a0row + kk * 16 + hi * 8);
        bf16x8 a1  = *(const bf16x8*)(ctx + a1row + kk * 16 + hi * 8);
        acc0 = MFMA32(a0, bfr, acc0);
        acc1 = MFMA32(a1, bfr, acc1);
    }
    const int e = eh * 128 + w * 32 + l31;
    #pragma unroll
    for (int r = 0; r < 16; ++r) {
        int crow = (r & 3) + 8 * (r >> 2) + 4 * hi;
        out[(size_t)(mt2 * 64 + crow) * 256 + e]      = acc0[r];
        out[(size_t)(mt2 * 64 + 32 + crow) * 256 + e] = acc1[r];
    }
}

// ---------------------------------------------------------------------------
extern "C" void kernel_launch(void* const* d_in, const int* in_sizes, int n_in,
                              void* d_out, int out_size, void* d_ws, size_t ws_size,
                              hipStream_t stream) {
    const float* x  = (const float*)d_in[0];  // [2][4096][256]
    const float* Qw = (const float*)d_in[1];  // [8][32][256]
    const float* Kw = (const float*)d_in[2];  // [8][32][256]
    const float* VO = (const float*)d_in[3];  // [8][256][256]
    float* out = (float*)d_out;               // [2][4096][256]

    char* ws = (char*)d_ws;
    __bf16* xT  = (__bf16*)(ws);                          // 4 MB  [2][256][4096]
    __bf16* qb  = (__bf16*)(ws + ((size_t)4 << 20));      // 4 MB  [2][8][4096][32]
    __bf16* kb  = (__bf16*)(ws + ((size_t)8 << 20));      // 4 MB
    __bf16* vot = (__bf16*)(ws + ((size_t)12 << 20));     // 1 MB  [256][2048]
    __bf16* ctx = (__bf16*)(ws + ((size_t)13 << 20));     // 32 MB [2][4096][8][256]

    prep<<<768, 256, 0, stream>>>(x, Qw, Kw, VO, xT, vot, qb, kb);
    attn_kernel<<<256, 512, 0, stream>>>(qb, kb, xT, ctx);
    gemm_out<<<256, 256, 0, stream>>>(ctx, vot, out);
}

// Round 12
// 255.306 us; speedup vs baseline: 1.3312x; 1.1490x over previous
//
#include <hip/hip_runtime.h>
#include <hip/hip_bf16.h>
#include <cstdint>
#include <cstddef>

typedef __attribute__((ext_vector_type(8))) __bf16 bf16x8;
typedef __attribute__((ext_vector_type(4))) float f32x4;
typedef __attribute__((ext_vector_type(16))) float f32x16;

#define MFMA16(a, b, c) __builtin_amdgcn_mfma_f32_16x16x32_bf16((a), (b), (c), 0, 0, 0)
#define MFMA32(a, b, c) __builtin_amdgcn_mfma_f32_32x32x16_bf16((a), (b), (c), 0, 0, 0)

__device__ __forceinline__ f32x16 zf16() {
    f32x16 z;
    #pragma unroll
    for (int r = 0; r < 16; ++r) z[r] = 0.f;
    return z;
}

__device__ __forceinline__ unsigned pk2(float lo, float hi) {
    unsigned w;
    asm("v_cvt_pk_bf16_f32 %0, %1, %2" : "=v"(w) : "v"(lo), "v"(hi));
    return w;
}
__device__ __forceinline__ void swap32(unsigned& a, unsigned& b) {
    asm("v_permlane32_swap_b32 %0, %1" : "+v"(a), "+v"(b));
}
__device__ __forceinline__ bf16x8 mkfrag(unsigned a, unsigned b, unsigned c, unsigned d) {
    union { unsigned u[4]; bf16x8 v; } x;
    x.u[0] = a; x.u[1] = b; x.u[2] = c; x.u[3] = d;
    return x.v;
}

// ---------------------------------------------------------------------------
// prep (fused; round-8 version): blocks 0..511 = x transpose+cvt (xT + xrow);
// 512..639 = VO transpose; 640..895 = Q/K weight cvt (Q scaled by log2e/16).
// ---------------------------------------------------------------------------
__global__ __launch_bounds__(256) void prep(const float* __restrict__ x,
                                            const float* __restrict__ Qw,
                                            const float* __restrict__ Kw,
                                            const float* __restrict__ VO,
                                            __bf16* __restrict__ xT,
                                            __bf16* __restrict__ xrow,
                                            __bf16* __restrict__ wb,
                                            __bf16* __restrict__ vot) {
    __shared__ float tile[64][65];
    const int bid = blockIdx.x;
    if (bid < 512) {
        const int b = bid >> 8;
        const int rem = bid & 255;
        const int tt = rem >> 2, dd = rem & 3;
        const int t0 = tt * 64, d0 = dd * 64;
        #pragma unroll
        for (int j = 0; j < 16; ++j) {
            int idx = j * 256 + threadIdx.x;
            int t = idx >> 6, d = idx & 63;
            float v = x[((size_t)(b * 4096 + t0 + t)) * 256 + d0 + d];
            tile[t][d] = v;
            xrow[((size_t)(b * 4096 + t0 + t)) * 256 + d0 + d] = (__bf16)v;
        }
        __syncthreads();
        #pragma unroll
        for (int j = 0; j < 16; ++j) {
            int idx = j * 256 + threadIdx.x;
            int d = idx >> 6, t = idx & 63;
            xT[((size_t)(b * 256 + d0 + d)) * 4096 + t0 + t] = (__bf16)tile[t][d];
        }
    } else if (bid < 640) {
        const int k = bid - 512;
        const int h = k >> 4;
        const int rem = k & 15;
        const int dt = rem >> 2, et = rem & 3;
        const int d0 = dt * 64, e0 = et * 64;
        #pragma unroll
        for (int j = 0; j < 16; ++j) {
            int idx = j * 256 + threadIdx.x;
            int d = idx >> 6, e = idx & 63;
            tile[d][e] = VO[((size_t)(h * 256 + d0 + d)) * 256 + e0 + e];
        }
        __syncthreads();
        #pragma unroll
        for (int j = 0; j < 16; ++j) {
            int idx = j * 256 + threadIdx.x;
            int e = idx >> 6, d = idx & 63;
            vot[((size_t)(e0 + e)) * 2048 + h * 256 + d0 + d] = (__bf16)tile[d][e];
        }
    } else {
        const float cl = 1.4426950408889634f / 16.0f;
        #pragma unroll
        for (int e = 0; e < 2; ++e) {
            int i = (bid - 640) * 512 + e * 256 + threadIdx.x;
            float v = (i < 65536) ? Qw[i] * cl : Kw[i - 65536];
            wb[i] = (__bf16)v;
        }
    }
}

// ---------------------------------------------------------------------------
// proj (round-8 version): block = 64 t-rows (4 waves x 16 rows); wave keeps
// its 16-row x A-fragments in registers, loops 16 (h,s) tasks (bf16 weights).
// ---------------------------------------------------------------------------
__global__ __launch_bounds__(256) void proj_kernel(const __bf16* __restrict__ xrow,
                                                   const __bf16* __restrict__ wb,
                                                   __bf16* __restrict__ qo,
                                                   __bf16* __restrict__ ko) {
    const int w = threadIdx.x >> 6;
    const int l = threadIdx.x & 63;
    const int g = l >> 4, c = l & 15;
    const int tg = blockIdx.x * 64 + w * 16;

    bf16x8 af[8];
    #pragma unroll
    for (int kk = 0; kk < 8; ++kk)
        af[kk] = *(const bf16x8*)(xrow + (size_t)(tg + c) * 256 + kk * 32 + g * 8);

    const int b = tg >> 12, t = tg & 4095;
    #pragma unroll
    for (int hs = 0; hs < 16; ++hs) {
        const int h = hs >> 1, s = hs & 1;
        const __bf16* W = wb + (size_t)(s * 8 + h) * 8192;  // [32][256]
        f32x4 acc0 = {0.f, 0.f, 0.f, 0.f}, acc1 = {0.f, 0.f, 0.f, 0.f};
        #pragma unroll
        for (int kk = 0; kk < 8; ++kk) {
            bf16x8 b0 = *(const bf16x8*)(W + (size_t)c * 256 + kk * 32 + g * 8);
            bf16x8 b1 = *(const bf16x8*)(W + (size_t)(16 + c) * 256 + kk * 32 + g * 8);
            acc0 = MFMA16(af[kk], b0, acc0);
            acc1 = MFMA16(af[kk], b1, acc1);
        }
        __bf16* outp = s ? ko : qo;
        const size_t obase = (size_t)(b * 8 + h) * 4096 + t;
        #pragma unroll
        for (int i = 0; i < 4; ++i) {
            outp[(obase + 4 * g + i) * 32 + c]      = (__bf16)acc0[i];
            outp[(obase + 4 * g + i) * 32 + 16 + c] = (__bf16)acc1[i];
        }
    }
}

// ---------------------------------------------------------------------------
// attn v11: 4-wave block (256 thr), grid 256 -> 1 wave/SIMD -> full 512-reg
// file per wave. Wave owns 64 q-rows x 256 d (acc = 256 regs); each x
// B-fragment read feeds TWO PV MFMAs (q-halves) -> per-tile LDS reads halved
// vs v8 (32 b128/wave, 128/block). No-max softmax; counted vmcnt(4) barrier.
// ---------------------------------------------------------------------------
__device__ __forceinline__ void stage_x(const __bf16* __restrict__ xTg_b,
                                        unsigned char* xbuf, int u0, int tid) {
    #pragma unroll
    for (int j = 0; j < 8; ++j) {
        int ch = j * 256 + tid;
        int d = ch >> 3;
        int slog = (ch & 7) ^ (d & 7);
        const __bf16* src = xTg_b + (size_t)d * 4096 + u0 + slog * 8;
        unsigned char* dst = xbuf + (size_t)(j * 256 + (tid & ~63)) * 16;  // wave-uniform
        __builtin_amdgcn_global_load_lds(
            (const __attribute__((address_space(1))) unsigned int*)src,
            (__attribute__((address_space(3))) unsigned int*)dst, 16, 0, 0);
    }
}

#define MKFRAG(dst, V, base)                                   \
    {                                                          \
        unsigned wa = pk2(V[(base) + 0], V[(base) + 1]);       \
        unsigned wb_ = pk2(V[(base) + 2], V[(base) + 3]);      \
        unsigned wc = pk2(V[(base) + 4], V[(base) + 5]);       \
        unsigned wd = pk2(V[(base) + 6], V[(base) + 7]);       \
        swap32(wa, wc);                                        \
        swap32(wb_, wd);                                       \
        dst = mkfrag(wa, wb_, wc, wd);                         \
    }

__global__ __launch_bounds__(256, 1) void attn_kernel(const __bf16* __restrict__ qg,
                                                      const __bf16* __restrict__ kg,
                                                      const __bf16* __restrict__ xTg,
                                                      __bf16* __restrict__ ctx) {
    __shared__ __align__(16) unsigned char lds[65536 + 1024];
    unsigned char* xbuf0 = lds;
    unsigned char* xbuf1 = lds + 32768;

    const int bid = blockIdx.x;
    const int bh = bid >> 4;
    const int tt = bid & 15;
    const int b = bh >> 3, h = bh & 7;
    const int t0 = tt * 256;
    const int tid = threadIdx.x;     // 0..255
    const int w = tid >> 6;          // 0..3 : q-rows [t0+w*64, +64)
    const int l = tid & 63;
    const int l31 = l & 31, hi = l >> 5;

    float* scale_w = (float*)(lds + 65536) + w * 64;

    const __bf16* xTg_b = xTg + (size_t)b * 256 * 4096;
    const __bf16* kg_bh = kg + (size_t)bh * 4096 * 32;

    // Q B-fragments for both 32-row q-halves
    bf16x8 qf[2][2];
    #pragma unroll
    for (int qh = 0; qh < 2; ++qh) {
        const size_t qoff = ((size_t)bh * 4096 + t0 + w * 64 + qh * 32 + l31) * 32;
        qf[qh][0] = *(const bf16x8*)(qg + qoff + hi * 8);
        qf[qh][1] = *(const bf16x8*)(qg + qoff + 16 + hi * 8);
    }

    f32x16 acc[2][8];
    #pragma unroll
    for (int qh = 0; qh < 2; ++qh)
        #pragma unroll
        for (int n = 0; n < 8; ++n)
            acc[qh][n] = zf16();

    float lsum0 = 0.f, lsum1 = 0.f;
    const int swz = (l31 & 7) << 4;

    bf16x8 kA[2][2];
    #pragma unroll
    for (int s = 0; s < 2; ++s)
        #pragma unroll
        for (int st = 0; st < 2; ++st)
            kA[s][st] = *(const bf16x8*)(kg_bh + (size_t)(s * 32 + l31) * 32 + st * 16 + hi * 8);

    stage_x(xTg_b, xbuf0, 0, tid);
    __syncthreads();

    for (int ut = 0; ut < 64; ++ut) {
        unsigned char* xcur = (ut & 1) ? xbuf1 : xbuf0;
        unsigned char* xnxt = (ut & 1) ? xbuf0 : xbuf1;
        if (ut < 63) stage_x(xTg_b, xnxt, (ut + 1) * 64, tid);

        bf16x8 pf0[4], pf1[4];
        // ---- q-half 0: QK -> exp2 -> pack (scores die before q-half 1) ----
        {
            f32x16 s0 = MFMA32(kA[0][0], qf[0][0], zf16());
            s0 = MFMA32(kA[0][1], qf[0][1], s0);
            f32x16 s1 = MFMA32(kA[1][0], qf[0][0], zf16());
            s1 = MFMA32(kA[1][1], qf[0][1], s1);
            float rs = 0.f;
            #pragma unroll
            for (int r = 0; r < 16; ++r) {
                float p;
                p = __builtin_amdgcn_exp2f(s0[r]); s0[r] = p; rs += p;
                p = __builtin_amdgcn_exp2f(s1[r]); s1[r] = p; rs += p;
            }
            lsum0 += rs;
            MKFRAG(pf0[0], s0, 0);
            MKFRAG(pf0[1], s0, 8);
            MKFRAG(pf0[2], s1, 0);
            MKFRAG(pf0[3], s1, 8);
        }
        // ---- q-half 1 ----
        {
            f32x16 s0 = MFMA32(kA[0][0], qf[1][0], zf16());
            s0 = MFMA32(kA[0][1], qf[1][1], s0);
            f32x16 s1 = MFMA32(kA[1][0], qf[1][0], zf16());
            s1 = MFMA32(kA[1][1], qf[1][1], s1);
            float rs = 0.f;
            #pragma unroll
            for (int r = 0; r < 16; ++r) {
                float p;
                p = __builtin_amdgcn_exp2f(s0[r]); s0[r] = p; rs += p;
                p = __builtin_amdgcn_exp2f(s1[r]); s1[r] = p; rs += p;
            }
            lsum1 += rs;
            MKFRAG(pf1[0], s0, 0);
            MKFRAG(pf1[1], s0, 8);
            MKFRAG(pf1[2], s1, 0);
            MKFRAG(pf1[3], s1, 8);
        }

        if (ut < 63) {  // prefetch next k-tile fragments (newest 4 vmem ops)
            const __bf16* kp = kg_bh + (size_t)(ut + 1) * 64 * 32;
            #pragma unroll
            for (int s = 0; s < 2; ++s)
                #pragma unroll
                for (int st = 0; st < 2; ++st)
                    kA[s][st] = *(const bf16x8*)(kp + (size_t)(s * 32 + l31) * 32 + st * 16 + hi * 8);
        }

        // ---- PV: each xb feeds both q-halves (32 b128 reads, 64 MFMA) ----
        __builtin_amdgcn_s_setprio(1);
        #pragma unroll
        for (int kk = 0; kk < 4; ++kk) {
            #pragma unroll
            for (int n = 0; n < 8; ++n) {
                const bf16x8 xb = *(const bf16x8*)(xcur + (n * 32 + l31) * 128 +
                                                   ((kk * 32 + hi * 16) ^ swz));
                acc[0][n] = MFMA32(pf0[kk], xb, acc[0][n]);
                acc[1][n] = MFMA32(pf1[kk], xb, acc[1][n]);
            }
        }
        __builtin_amdgcn_s_setprio(0);

        // counted barrier: drain the 8 stage loads, keep kA prefetch in flight
        asm volatile("s_waitcnt vmcnt(4)" ::: "memory");
        __builtin_amdgcn_s_barrier();
    }

    // ---- epilogue: combine lsum halves, broadcast 1/lsum by q-row ----
    lsum0 += __shfl_xor(lsum0, 32);
    lsum1 += __shfl_xor(lsum1, 32);
    if (!hi) {
        scale_w[l31]      = 1.0f / lsum0;
        scale_w[32 + l31] = 1.0f / lsum1;
    }
    #pragma unroll
    for (int qh = 0; qh < 2; ++qh) {
        f32x4 iv[4];
        #pragma unroll
        for (int q4 = 0; q4 < 4; ++q4)
            iv[q4] = *(const f32x4*)&scale_w[qh * 32 + q4 * 8 + hi * 4];
        #pragma unroll
        for (int n = 0; n < 8; ++n) {
            #pragma unroll
            for (int r = 0; r < 16; ++r) {
                int t = t0 + w * 64 + qh * 32 + (r & 3) + 8 * (r >> 2) + 4 * hi;
                int d = n * 32 + l31;
                ctx[((size_t)(b * 4096 + t) * 8 + h) * 256 + d] =
                    (__bf16)(acc[qh][n][r] * iv[r >> 2][r & 3]);
            }
        }
    }
}

// ---------------------------------------------------------------------------
// gemm_out: out[bt][e] = sum_k ctx[bt][k] * VOT[e][k]; M=8192 K=2048 N=256.
// block = 64 m-rows x 128 e (4 waves; wave = 2 m-tiles x 32 e).
// ---------------------------------------------------------------------------
__global__ __launch_bounds__(256) void gemm_out(const __bf16* __restrict__ ctx,
                                                const __bf16* __restrict__ vot,
                                                float* __restrict__ out) {
    const int bid = blockIdx.x;
    const int mt2 = bid >> 1;
    const int eh = bid & 1;
    const int w = threadIdx.x >> 6;
    const int l = threadIdx.x & 63;
    const int l31 = l & 31, hi = l >> 5;
    const size_t a0row = (size_t)(mt2 * 64 + l31) * 2048;
    const size_t a1row = (size_t)(mt2 * 64 + 32 + l31) * 2048;
    const size_t brow  = (size_t)(eh * 128 + w * 32 + l31) * 2048;
    f32x16 acc0 = zf16(), acc1 = zf16();
    #pragma unroll 4
    for (int kk = 0; kk < 128; ++kk) {
        bf16x8 bfr = *(const bf16x8*)(vot + brow + kk * 16 + hi * 8);
        bf16x8 a0  = *(const bf16x8*)(ctx + a0row + kk * 16 + hi * 8);
        bf16x8 a1  = *(const bf16x8*)(ctx + a1row + kk * 16 + hi * 8);
        acc0 = MFMA32(a0, bfr, acc0);
        acc1 = MFMA32(a1, bfr, acc1);
    }
    const int e = eh * 128 + w * 32 + l31;
    #pragma unroll
    for (int r = 0; r < 16; ++r) {
        int crow = (r & 3) + 8 * (r >> 2) + 4 * hi;
        out[(size_t)(mt2 * 64 + crow) * 256 + e]      = acc0[r];
        out[(size_t)(mt2 * 64 + 32 + crow) * 256 + e] = acc1[r];
    }
}

// ---------------------------------------------------------------------------
extern "C" void kernel_launch(void* const* d_in, const int* in_sizes, int n_in,
                              void* d_out, int out_size, void* d_ws, size_t ws_size,
                              hipStream_t stream) {
    const float* x  = (const float*)d_in[0];  // [2][4096][256]
    const float* Qw = (const float*)d_in[1];  // [8][32][256]
    const float* Kw = (const float*)d_in[2];  // [8][32][256]
    const float* VO = (const float*)d_in[3];  // [8][256][256]
    float* out = (float*)d_out;               // [2][4096][256]

    char* ws = (char*)d_ws;
    __bf16* xT   = (__bf16*)(ws);                          // 4 MB  [2][256][4096]
    __bf16* xrow = (__bf16*)(ws + ((size_t)4 << 20));      // 4 MB  [2][4096][256]
    __bf16* qb   = (__bf16*)(ws + ((size_t)8 << 20));      // 4 MB  [2][8][4096][32]
    __bf16* kb   = (__bf16*)(ws + ((size_t)12 << 20));     // 4 MB
    __bf16* wb   = (__bf16*)(ws + ((size_t)16 << 20));     // 256 KB [2][8][32][256]
    __bf16* vot  = (__bf16*)(ws + ((size_t)17 << 20));     // 1 MB  [256][2048]
    __bf16* ctx  = (__bf16*)(ws + ((size_t)18 << 20));     // 32 MB [2][4096][8][256]

    prep<<<896, 256, 0, stream>>>(x, Qw, Kw, VO, xT, xrow, wb, vot);
    proj_kernel<<<128, 256, 0, stream>>>(xrow, wb, qb, kb);
    attn_kernel<<<256, 256, 0, stream>>>(qb, kb, xT, ctx);
    gemm_out<<<256, 256, 0, stream>>>(ctx, vot, out);
}

// Round 13
// 240.595 us; speedup vs baseline: 1.4126x; 1.0611x over previous
//
#include <hip/hip_runtime.h>
#include <hip/hip_bf16.h>
#include <cstdint>
#include <cstddef>

typedef __attribute__((ext_vector_type(8))) __bf16 bf16x8;
typedef __attribute__((ext_vector_type(4))) float f32x4;
typedef __attribute__((ext_vector_type(16))) float f32x16;

#define MFMA16(a, b, c) __builtin_amdgcn_mfma_f32_16x16x32_bf16((a), (b), (c), 0, 0, 0)
#define MFMA32(a, b, c) __builtin_amdgcn_mfma_f32_32x32x16_bf16((a), (b), (c), 0, 0, 0)

__device__ __forceinline__ f32x16 zf16() {
    f32x16 z;
    #pragma unroll
    for (int r = 0; r < 16; ++r) z[r] = 0.f;
    return z;
}

__device__ __forceinline__ unsigned pk2(float lo, float hi) {
    unsigned w;
    asm("v_cvt_pk_bf16_f32 %0, %1, %2" : "=v"(w) : "v"(lo), "v"(hi));
    return w;
}
__device__ __forceinline__ void swap32(unsigned& a, unsigned& b) {
    asm("v_permlane32_swap_b32 %0, %1" : "+v"(a), "+v"(b));
}
__device__ __forceinline__ bf16x8 mkfrag(unsigned a, unsigned b, unsigned c, unsigned d) {
    union { unsigned u[4]; bf16x8 v; } x;
    x.u[0] = a; x.u[1] = b; x.u[2] = c; x.u[3] = d;
    return x.v;
}

// ---------------------------------------------------------------------------
// prep (round-8): blocks 0..511 = x transpose+cvt (xT + xrow);
// 512..639 = VO transpose; 640..895 = Q/K weight cvt (Q scaled by log2e/16).
// ---------------------------------------------------------------------------
__global__ __launch_bounds__(256) void prep(const float* __restrict__ x,
                                            const float* __restrict__ Qw,
                                            const float* __restrict__ Kw,
                                            const float* __restrict__ VO,
                                            __bf16* __restrict__ xT,
                                            __bf16* __restrict__ xrow,
                                            __bf16* __restrict__ wb,
                                            __bf16* __restrict__ vot) {
    __shared__ float tile[64][65];
    const int bid = blockIdx.x;
    if (bid < 512) {
        const int b = bid >> 8;
        const int rem = bid & 255;
        const int tt = rem >> 2, dd = rem & 3;
        const int t0 = tt * 64, d0 = dd * 64;
        #pragma unroll
        for (int j = 0; j < 16; ++j) {
            int idx = j * 256 + threadIdx.x;
            int t = idx >> 6, d = idx & 63;
            float v = x[((size_t)(b * 4096 + t0 + t)) * 256 + d0 + d];
            tile[t][d] = v;
            xrow[((size_t)(b * 4096 + t0 + t)) * 256 + d0 + d] = (__bf16)v;
        }
        __syncthreads();
        #pragma unroll
        for (int j = 0; j < 16; ++j) {
            int idx = j * 256 + threadIdx.x;
            int d = idx >> 6, t = idx & 63;
            xT[((size_t)(b * 256 + d0 + d)) * 4096 + t0 + t] = (__bf16)tile[t][d];
        }
    } else if (bid < 640) {
        const int k = bid - 512;
        const int h = k >> 4;
        const int rem = k & 15;
        const int dt = rem >> 2, et = rem & 3;
        const int d0 = dt * 64, e0 = et * 64;
        #pragma unroll
        for (int j = 0; j < 16; ++j) {
            int idx = j * 256 + threadIdx.x;
            int d = idx >> 6, e = idx & 63;
            tile[d][e] = VO[((size_t)(h * 256 + d0 + d)) * 256 + e0 + e];
        }
        __syncthreads();
        #pragma unroll
        for (int j = 0; j < 16; ++j) {
            int idx = j * 256 + threadIdx.x;
            int e = idx >> 6, d = idx & 63;
            vot[((size_t)(e0 + e)) * 2048 + h * 256 + d0 + d] = (__bf16)tile[d][e];
        }
    } else {
        const float cl = 1.4426950408889634f / 16.0f;
        #pragma unroll
        for (int e = 0; e < 2; ++e) {
            int i = (bid - 640) * 512 + e * 256 + threadIdx.x;
            float v = (i < 65536) ? Qw[i] * cl : Kw[i - 65536];
            wb[i] = (__bf16)v;
        }
    }
}

// ---------------------------------------------------------------------------
// proj (round-8): block = 64 t-rows (4 waves x 16 rows); wave keeps its
// 16-row x A-fragments in registers, loops 16 (h,s) tasks (bf16 weights).
// ---------------------------------------------------------------------------
__global__ __launch_bounds__(256) void proj_kernel(const __bf16* __restrict__ xrow,
                                                   const __bf16* __restrict__ wb,
                                                   __bf16* __restrict__ qo,
                                                   __bf16* __restrict__ ko) {
    const int w = threadIdx.x >> 6;
    const int l = threadIdx.x & 63;
    const int g = l >> 4, c = l & 15;
    const int tg = blockIdx.x * 64 + w * 16;

    bf16x8 af[8];
    #pragma unroll
    for (int kk = 0; kk < 8; ++kk)
        af[kk] = *(const bf16x8*)(xrow + (size_t)(tg + c) * 256 + kk * 32 + g * 8);

    const int b = tg >> 12, t = tg & 4095;
    #pragma unroll
    for (int hs = 0; hs < 16; ++hs) {
        const int h = hs >> 1, s = hs & 1;
        const __bf16* W = wb + (size_t)(s * 8 + h) * 8192;  // [32][256]
        f32x4 acc0 = {0.f, 0.f, 0.f, 0.f}, acc1 = {0.f, 0.f, 0.f, 0.f};
        #pragma unroll
        for (int kk = 0; kk < 8; ++kk) {
            bf16x8 b0 = *(const bf16x8*)(W + (size_t)c * 256 + kk * 32 + g * 8);
            bf16x8 b1 = *(const bf16x8*)(W + (size_t)(16 + c) * 256 + kk * 32 + g * 8);
            acc0 = MFMA16(af[kk], b0, acc0);
            acc1 = MFMA16(af[kk], b1, acc1);
        }
        __bf16* outp = s ? ko : qo;
        const size_t obase = (size_t)(b * 8 + h) * 4096 + t;
        #pragma unroll
        for (int i = 0; i < 4; ++i) {
            outp[(obase + 4 * g + i) * 32 + c]      = (__bf16)acc0[i];
            outp[(obase + 4 * g + i) * 32 + 16 + c] = (__bf16)acc1[i];
        }
    }
}

// ---------------------------------------------------------------------------
// attn v12: v8 per-wave structure (8 waves, 32 q-rows/wave, 2 waves/SIMD)
// with UBLK=128: stage 64KB x-tiles (dbuf 2x64KB LDS), run TWO v8 bodies
// per barrier (u 0..63, 64..127) -> half the barrier/lockstep tax.
// Register profile identical to v8 (kA reloaded in place; per-sub regs die).
// grid = 256 blocks x 512 threads (1 block/CU)
// ---------------------------------------------------------------------------
__device__ __forceinline__ void stage_x128(const __bf16* __restrict__ xTg_b,
                                           unsigned char* xbuf, int u0, int tid) {
    #pragma unroll
    for (int j = 0; j < 8; ++j) {
        int ch = j * 512 + tid;          // 0..4095 chunks of 16B
        int d = ch >> 4;                 // 256 rows of 256B
        int c16 = ch & 15;
        int slog = (c16 & 8) | ((c16 ^ (d & 7)) & 7);
        const __bf16* src = xTg_b + (size_t)d * 4096 + u0 + slog * 8;
        unsigned char* dst = xbuf + (size_t)(j * 512 + (tid & ~63)) * 16;  // wave-uniform
        __builtin_amdgcn_global_load_lds(
            (const __attribute__((address_space(1))) unsigned int*)src,
            (__attribute__((address_space(3))) unsigned int*)dst, 16, 0, 0);
    }
}

#define MKFRAG(dst, V, base)                                   \
    {                                                          \
        unsigned wa = pk2(V[(base) + 0], V[(base) + 1]);       \
        unsigned wb_ = pk2(V[(base) + 2], V[(base) + 3]);      \
        unsigned wc = pk2(V[(base) + 4], V[(base) + 5]);       \
        unsigned wd = pk2(V[(base) + 6], V[(base) + 7]);       \
        swap32(wa, wc);                                        \
        swap32(wb_, wd);                                       \
        dst = mkfrag(wa, wb_, wc, wd);                         \
    }

// one v8 body over a 64-u half-tile: QK -> prefetch kA(next_u) -> exp2 ->
// pack -> PV (kk0..kk0+3).  PREF guards the kA reload.
#define SUBBODY(XCUR, KK0, NEXT_U, PREF)                                       \
    {                                                                          \
        f32x16 s0 = MFMA32(kA[0][0], qf0, zf16());                             \
        s0 = MFMA32(kA[0][1], qf1, s0);                                        \
        f32x16 s1 = MFMA32(kA[1][0], qf0, zf16());                             \
        s1 = MFMA32(kA[1][1], qf1, s1);                                        \
        if (PREF) {                                                            \
            const __bf16* kp = kg_bh + (size_t)(NEXT_U) * 32;                  \
            _Pragma("unroll")                                                  \
            for (int s = 0; s < 2; ++s)                                        \
                _Pragma("unroll")                                              \
                for (int st = 0; st < 2; ++st)                                 \
                    kA[s][st] = *(const bf16x8*)(kp +                          \
                        (size_t)(s * 32 + l31) * 32 + st * 16 + hi * 8);       \
        }                                                                      \
        float rs = 0.f;                                                        \
        _Pragma("unroll")                                                      \
        for (int r = 0; r < 16; ++r) {                                         \
            float p = __builtin_amdgcn_exp2f(s0[r]);                           \
            s0[r] = p; rs += p;                                                \
        }                                                                      \
        _Pragma("unroll")                                                      \
        for (int r = 0; r < 16; ++r) {                                         \
            float p = __builtin_amdgcn_exp2f(s1[r]);                           \
            s1[r] = p; rs += p;                                                \
        }                                                                      \
        lsum += rs;                                                            \
        bf16x8 pf[4];                                                          \
        MKFRAG(pf[0], s0, 0);                                                  \
        MKFRAG(pf[1], s0, 8);                                                  \
        MKFRAG(pf[2], s1, 0);                                                  \
        MKFRAG(pf[3], s1, 8);                                                  \
        __builtin_amdgcn_s_setprio(1);                                         \
        _Pragma("unroll")                                                      \
        for (int kk = 0; kk < 4; ++kk) {                                       \
            _Pragma("unroll")                                                  \
            for (int n = 0; n < 8; ++n) {                                      \
                const bf16x8 xb = *(const bf16x8*)((XCUR) +                    \
                    (n * 32 + l31) * 256 +                                     \
                    ((((KK0) + kk) * 32 + hi * 16) ^ swz));                    \
                acc[n] = MFMA32(pf[kk], xb, acc[n]);                           \
            }                                                                  \
        }                                                                      \
        __builtin_amdgcn_s_setprio(0);                                         \
    }

__global__ __launch_bounds__(512, 2) void attn_kernel(const __bf16* __restrict__ qg,
                                                      const __bf16* __restrict__ kg,
                                                      const __bf16* __restrict__ xTg,
                                                      __bf16* __restrict__ ctx) {
    __shared__ __align__(16) unsigned char lds[131072 + 1024];
    unsigned char* xbuf0 = lds;
    unsigned char* xbuf1 = lds + 65536;

    const int bid = blockIdx.x;
    const int bh = bid >> 4;
    const int tt = bid & 15;
    const int b = bh >> 3, h = bh & 7;
    const int t0 = tt * 256;
    const int tid = threadIdx.x;
    const int w = tid >> 6;
    const int l = tid & 63;
    const int l31 = l & 31, hi = l >> 5;

    float* scale_w = (float*)(lds + 131072) + w * 32;

    const __bf16* xTg_b = xTg + (size_t)b * 256 * 4096;
    const __bf16* kg_bh = kg + (size_t)bh * 4096 * 32;

    const size_t qoff = ((size_t)bh * 4096 + t0 + w * 32 + l31) * 32;
    const bf16x8 qf0 = *(const bf16x8*)(qg + qoff + hi * 8);
    const bf16x8 qf1 = *(const bf16x8*)(qg + qoff + 16 + hi * 8);

    f32x16 acc[8];
    #pragma unroll
    for (int n = 0; n < 8; ++n)
        #pragma unroll
        for (int r = 0; r < 16; ++r) acc[n][r] = 0.f;

    float lsum = 0.f;
    const int swz = (l31 & 7) << 4;

    bf16x8 kA[2][2];
    #pragma unroll
    for (int s = 0; s < 2; ++s)
        #pragma unroll
        for (int st = 0; st < 2; ++st)
            kA[s][st] = *(const bf16x8*)(kg_bh + (size_t)(s * 32 + l31) * 32 + st * 16 + hi * 8);

    stage_x128(xTg_b, xbuf0, 0, tid);
    __syncthreads();

    for (int ut = 0; ut < 32; ++ut) {
        unsigned char* xcur = (ut & 1) ? xbuf1 : xbuf0;
        unsigned char* xnxt = (ut & 1) ? xbuf0 : xbuf1;
        if (ut < 31) stage_x128(xTg_b, xnxt, (ut + 1) * 128, tid);

        // sub-body A: u = ut*128 .. +63 ; prefetch kA for half B (always valid)
        SUBBODY(xcur, 0, ut * 128 + 64, 1)
        // sub-body B: u = ut*128+64 .. +127 ; prefetch kA for next tile
        SUBBODY(xcur, 4, (ut + 1) * 128, ut < 31)

        // drain the 8 stage loads (oldest); keep newest 4 kA loads in flight
        asm volatile("s_waitcnt vmcnt(4)" ::: "memory");
        __builtin_amdgcn_s_barrier();
    }

    // ---- epilogue: combine lsum across lane halves, broadcast 1/lsum ----
    lsum += __shfl_xor(lsum, 32);
    const float linv = 1.0f / lsum;
    if (!hi) scale_w[l31] = linv;
    f32x4 iv[4];
    #pragma unroll
    for (int q4 = 0; q4 < 4; ++q4)
        iv[q4] = *(const f32x4*)&scale_w[q4 * 8 + hi * 4];
    #pragma unroll
    for (int n = 0; n < 8; ++n) {
        #pragma unroll
        for (int r = 0; r < 16; ++r) {
            int t = t0 + w * 32 + (r & 3) + 8 * (r >> 2) + 4 * hi;
            int d = n * 32 + l31;
            ctx[((size_t)(b * 4096 + t) * 8 + h) * 256 + d] =
                (__bf16)(acc[n][r] * iv[r >> 2][r & 3]);
        }
    }
}

// ---------------------------------------------------------------------------
// gemm_out (round-8): out[bt][e] = sum_k ctx[bt][k] * VOT[e][k].
// block = 64 m-rows x 128 e (4 waves; wave = 2 m-tiles x 32 e).
// ---------------------------------------------------------------------------
__global__ __launch_bounds__(256) void gemm_out(const __bf16* __restrict__ ctx,
                                                const __bf16* __restrict__ vot,
                                                float* __restrict__ out) {
    const int bid = blockIdx.x;
    const int mt2 = bid >> 1;
    const int eh = bid & 1;
    const int w = threadIdx.x >> 6;
    const int l = threadIdx.x & 63;
    const int l31 = l & 31, hi = l >> 5;
    const size_t a0row = (size_t)(mt2 * 64 + l31) * 2048;
    const size_t a1row = (size_t)(mt2 * 64 + 32 + l31) * 2048;
    const size_t brow  = (size_t)(eh * 128 + w * 32 + l31) * 2048;
    f32x16 acc0 = zf16(), acc1 = zf16();
    #pragma unroll 4
    for (int kk = 0; kk < 128; ++kk) {
        bf16x8 bfr = *(const bf16x8*)(vot + brow + kk * 16 + hi * 8);
        bf16x8 a0  = *(const bf16x8*)(ctx + a0row + kk * 16 + hi * 8);
        bf16x8 a1  = *(const bf16x8*)(ctx + a1row + kk * 16 + hi * 8);
        acc0 = MFMA32(a0, bfr, acc0);
        acc1 = MFMA32(a1, bfr, acc1);
    }
    const int e = eh * 128 + w * 32 + l31;
    #pragma unroll
    for (int r = 0; r < 16; ++r) {
        int crow = (r & 3) + 8 * (r >> 2) + 4 * hi;
        out[(size_t)(mt2 * 64 + crow) * 256 + e]      = acc0[r];
        out[(size_t)(mt2 * 64 + 32 + crow) * 256 + e] = acc1[r];
    }
}

// ---------------------------------------------------------------------------
extern "C" void kernel_launch(void* const* d_in, const int* in_sizes, int n_in,
                              void* d_out, int out_size, void* d_ws, size_t ws_size,
                              hipStream_t stream) {
    const float* x  = (const float*)d_in[0];  // [2][4096][256]
    const float* Qw = (const float*)d_in[1];  // [8][32][256]
    const float* Kw = (const float*)d_in[2];  // [8][32][256]
    const float* VO = (const float*)d_in[3];  // [8][256][256]
    float* out = (float*)d_out;               // [2][4096][256]

    char* ws = (char*)d_ws;
    __bf16* xT   = (__bf16*)(ws);                          // 4 MB  [2][256][4096]
    __bf16* xrow = (__bf16*)(ws + ((size_t)4 << 20));      // 4 MB  [2][4096][256]
    __bf16* qb   = (__bf16*)(ws + ((size_t)8 << 20));      // 4 MB  [2][8][4096][32]
    __bf16* kb   = (__bf16*)(ws + ((size_t)12 << 20));     // 4 MB
    __bf16* wb   = (__bf16*)(ws + ((size_t)16 << 20));     // 256 KB [2][8][32][256]
    __bf16* vot  = (__bf16*)(ws + ((size_t)17 << 20));     // 1 MB  [256][2048]
    __bf16* ctx  = (__bf16*)(ws + ((size_t)18 << 20));     // 32 MB [2][4096][8][256]

    prep<<<896, 256, 0, stream>>>(x, Qw, Kw, VO, xT, xrow, wb, vot);
    proj_kernel<<<128, 256, 0, stream>>>(xrow, wb, qb, kb);
    attn_kernel<<<256, 512, 0, stream>>>(qb, kb, xT, ctx);
    gemm_out<<<256, 256, 0, stream>>>(ctx, vot, out);
}

// Round 14
// 213.371 us; speedup vs baseline: 1.5928x; 1.1276x over previous
//
#include <hip/hip_runtime.h>
#include <hip/hip_bf16.h>
#include <cstdint>
#include <cstddef>

typedef __attribute__((ext_vector_type(8))) __bf16 bf16x8;
typedef __attribute__((ext_vector_type(4))) float f32x4;
typedef __attribute__((ext_vector_type(16))) float f32x16;

#define MFMA16(a, b, c) __builtin_amdgcn_mfma_f32_16x16x32_bf16((a), (b), (c), 0, 0, 0)
#define MFMA32(a, b, c) __builtin_amdgcn_mfma_f32_32x32x16_bf16((a), (b), (c), 0, 0, 0)
#define MFMA8(a, b, c)  __builtin_amdgcn_mfma_f32_32x32x16_fp8_fp8((a), (b), (c), 0, 0, 0)

__device__ __forceinline__ f32x16 zf16() {
    f32x16 z;
    #pragma unroll
    for (int r = 0; r < 16; ++r) z[r] = 0.f;
    return z;
}

__device__ __forceinline__ void swap32(unsigned& a, unsigned& b) {
    asm("v_permlane32_swap_b32 %0, %1" : "+v"(a), "+v"(b));
}

// ---------------------------------------------------------------------------
// prep: blocks 0..511 = x -> x8T fp8 [2][256][4096] (transposed) + xrow bf16;
// 512..639 = VO transpose -> vot; 640..895 = Q/K weight cvt (Q scaled).
// ---------------------------------------------------------------------------
__global__ __launch_bounds__(256) void prep(const float* __restrict__ x,
                                            const float* __restrict__ Qw,
                                            const float* __restrict__ Kw,
                                            const float* __restrict__ VO,
                                            unsigned char* __restrict__ x8T,
                                            __bf16* __restrict__ xrow,
                                            __bf16* __restrict__ wb,
                                            __bf16* __restrict__ vot) {
    __shared__ float tile[64][65];
    const int bid = blockIdx.x;
    if (bid < 512) {
        const int b = bid >> 8;
        const int rem = bid & 255;
        const int tt = rem >> 2, dd = rem & 3;
        const int t0 = tt * 64, d0 = dd * 64;
        #pragma unroll
        for (int j = 0; j < 16; ++j) {
            int idx = j * 256 + threadIdx.x;
            int t = idx >> 6, d = idx & 63;
            float v = x[((size_t)(b * 4096 + t0 + t)) * 256 + d0 + d];
            tile[t][d] = v;
            xrow[((size_t)(b * 4096 + t0 + t)) * 256 + d0 + d] = (__bf16)v;
        }
        __syncthreads();
        #pragma unroll
        for (int j = 0; j < 8; ++j) {
            int idx = j * 256 + threadIdx.x;
            int d = idx >> 5, tp = idx & 31;      // d 0..63, t-pair 0..31
            float v0 = tile[tp * 2][d];
            float v1 = tile[tp * 2 + 1][d];
            int wpk = __builtin_amdgcn_cvt_pk_fp8_f32(v0, v1, 0, false);
            *(unsigned short*)(x8T + (size_t)(b * 256 + d0 + d) * 4096 + t0 + tp * 2) =
                (unsigned short)wpk;
        }
    } else if (bid < 640) {
        const int k = bid - 512;
        const int h = k >> 4;
        const int rem = k & 15;
        const int dt = rem >> 2, et = rem & 3;
        const int d0 = dt * 64, e0 = et * 64;
        #pragma unroll
        for (int j = 0; j < 16; ++j) {
            int idx = j * 256 + threadIdx.x;
            int d = idx >> 6, e = idx & 63;
            tile[d][e] = VO[((size_t)(h * 256 + d0 + d)) * 256 + e0 + e];
        }
        __syncthreads();
        #pragma unroll
        for (int j = 0; j < 16; ++j) {
            int idx = j * 256 + threadIdx.x;
            int e = idx >> 6, d = idx & 63;
            vot[((size_t)(e0 + e)) * 2048 + h * 256 + d0 + d] = (__bf16)tile[d][e];
        }
    } else {
        const float cl = 1.4426950408889634f / 16.0f;
        #pragma unroll
        for (int e = 0; e < 2; ++e) {
            int i = (bid - 640) * 512 + e * 256 + threadIdx.x;
            float v = (i < 65536) ? Qw[i] * cl : Kw[i - 65536];
            wb[i] = (__bf16)v;
        }
    }
}

// ---------------------------------------------------------------------------
// proj (round-8): block = 64 t-rows (4 waves x 16 rows); wave keeps its
// 16-row x A-fragments in registers, loops 16 (h,s) tasks (bf16 weights).
// ---------------------------------------------------------------------------
__global__ __launch_bounds__(256) void proj_kernel(const __bf16* __restrict__ xrow,
                                                   const __bf16* __restrict__ wb,
                                                   __bf16* __restrict__ qo,
                                                   __bf16* __restrict__ ko) {
    const int w = threadIdx.x >> 6;
    const int l = threadIdx.x & 63;
    const int g = l >> 4, c = l & 15;
    const int tg = blockIdx.x * 64 + w * 16;

    bf16x8 af[8];
    #pragma unroll
    for (int kk = 0; kk < 8; ++kk)
        af[kk] = *(const bf16x8*)(xrow + (size_t)(tg + c) * 256 + kk * 32 + g * 8);

    const int b = tg >> 12, t = tg & 4095;
    #pragma unroll
    for (int hs = 0; hs < 16; ++hs) {
        const int h = hs >> 1, s = hs & 1;
        const __bf16* W = wb + (size_t)(s * 8 + h) * 8192;  // [32][256]
        f32x4 acc0 = {0.f, 0.f, 0.f, 0.f}, acc1 = {0.f, 0.f, 0.f, 0.f};
        #pragma unroll
        for (int kk = 0; kk < 8; ++kk) {
            bf16x8 b0 = *(const bf16x8*)(W + (size_t)c * 256 + kk * 32 + g * 8);
            bf16x8 b1 = *(const bf16x8*)(W + (size_t)(16 + c) * 256 + kk * 32 + g * 8);
            acc0 = MFMA16(af[kk], b0, acc0);
            acc1 = MFMA16(af[kk], b1, acc1);
        }
        __bf16* outp = s ? ko : qo;
        const size_t obase = (size_t)(b * 8 + h) * 4096 + t;
        #pragma unroll
        for (int i = 0; i < 4; ++i) {
            outp[(obase + 4 * g + i) * 32 + c]      = (__bf16)acc0[i];
            outp[(obase + 4 * g + i) * 32 + 16 + c] = (__bf16)acc1[i];
        }
    }
}

// ---------------------------------------------------------------------------
// attn v13: v8 structure (8 waves, 32 q-rows/wave, 2 waves/SIMD, grid 256)
// with fp8 PV: P and x in e4m3, mfma_f32_32x32x16_fp8_fp8 (bf16 rate, half
// operand bytes) -> PV LDS reads halve (b64). x-tile [256d][64u] fp8, rows
// padded to 72B -> all LDS accesses 2-way-or-free (no XOR swizzle needed).
// Reg-staged x (global->reg at loop top, ds_write after PV). QK stays bf16.
// No-max softmax. grid = 256 blocks x 512 threads (1 block/CU)
// ---------------------------------------------------------------------------

// P C-layout regs -> fp8 A-frag (8 x e4m3 across 2 dwords, halves swapped)
#define MK8FRAG(dst, V, base)                                                  \
    {                                                                          \
        unsigned d0 = 0, d1 = 0;                                               \
        d0 = __builtin_amdgcn_cvt_pk_fp8_f32(V[(base) + 0], V[(base) + 1], d0, false); \
        d0 = __builtin_amdgcn_cvt_pk_fp8_f32(V[(base) + 2], V[(base) + 3], d0, true);  \
        d1 = __builtin_amdgcn_cvt_pk_fp8_f32(V[(base) + 4], V[(base) + 5], d1, false); \
        d1 = __builtin_amdgcn_cvt_pk_fp8_f32(V[(base) + 6], V[(base) + 7], d1, true);  \
        swap32(d0, d1);                                                        \
        union { unsigned u[2]; long l; } z;                                    \
        z.u[0] = d0; z.u[1] = d1;                                              \
        dst = z.l;                                                             \
    }

__global__ __launch_bounds__(512, 2) void attn_kernel(const __bf16* __restrict__ qg,
                                                      const __bf16* __restrict__ kg,
                                                      const unsigned char* __restrict__ x8g,
                                                      __bf16* __restrict__ ctx) {
    // x-tile buffers: [256 d][72 B] (64B fp8 data + 8B pad) x2 + scales
    __shared__ __align__(16) unsigned char lds[2 * 18432 + 1024];
    unsigned char* xbuf0 = lds;
    unsigned char* xbuf1 = lds + 18432;
    float* scale_base = (float*)(lds + 36864);

    const int bid = blockIdx.x;
    const int bh = bid >> 4;
    const int tt = bid & 15;
    const int b = bh >> 3, h = bh & 7;
    const int t0 = tt * 256;
    const int tid = threadIdx.x;
    const int w = tid >> 6;
    const int l = tid & 63;
    const int l31 = l & 31, hi = l >> 5;

    float* scale_w = scale_base + w * 32;

    const unsigned char* x8b = x8g + (size_t)b * 256 * 4096;
    const __bf16* kg_bh = kg + (size_t)bh * 4096 * 32;

    // staging geometry: thread covers 32B of the 16KB tile
    const int srow = tid >> 1;            // d row 0..255
    const int soff = (tid & 1) * 32;      // byte offset within 64B row

    const size_t qoff = ((size_t)bh * 4096 + t0 + w * 32 + l31) * 32;
    const bf16x8 qf0 = *(const bf16x8*)(qg + qoff + hi * 8);
    const bf16x8 qf1 = *(const bf16x8*)(qg + qoff + 16 + hi * 8);

    f32x16 acc[8];
    #pragma unroll
    for (int n = 0; n < 8; ++n)
        #pragma unroll
        for (int r = 0; r < 16; ++r) acc[n][r] = 0.f;

    float lsum = 0.f;

    bf16x8 kA[2][2];
    #pragma unroll
    for (int s = 0; s < 2; ++s)
        #pragma unroll
        for (int st = 0; st < 2; ++st)
            kA[s][st] = *(const bf16x8*)(kg_bh + (size_t)(s * 32 + l31) * 32 + st * 16 + hi * 8);

    // prologue: stage tile 0 into xbuf0
    {
        const unsigned char* sp = x8b + (size_t)srow * 4096 + soff;
        uint4 la = *(const uint4*)sp;
        uint4 lb = *(const uint4*)(sp + 16);
        unsigned char* dp = xbuf0 + srow * 72 + soff;
        union { uint4 v; unsigned long long q[2]; } ua, ub;
        ua.v = la; ub.v = lb;
        ((unsigned long long*)dp)[0] = ua.q[0];
        ((unsigned long long*)dp)[1] = ua.q[1];
        ((unsigned long long*)(dp + 16))[0] = ub.q[0];
        ((unsigned long long*)(dp + 16))[1] = ub.q[1];
    }
    __syncthreads();

    for (int ut = 0; ut < 64; ++ut) {
        unsigned char* xcur = (ut & 1) ? xbuf1 : xbuf0;
        unsigned char* xnxt = (ut & 1) ? xbuf0 : xbuf1;

        // issue next-tile stage loads (wrap on last iter; write is harmless)
        const int u_next = ((ut + 1) & 63) * 64;
        const unsigned char* sp = x8b + (size_t)srow * 4096 + u_next + soff;
        const uint4 la = *(const uint4*)sp;
        const uint4 lb = *(const uint4*)(sp + 16);

        // ---- S^T = K * Q^T (bf16, log2-domain, scale pre-folded in Q) ----
        f32x16 s0 = MFMA32(kA[0][0], qf0, zf16());
        s0 = MFMA32(kA[0][1], qf1, s0);
        f32x16 s1 = MFMA32(kA[1][0], qf0, zf16());
        s1 = MFMA32(kA[1][1], qf1, s1);

        if (ut < 63) {  // prefetch next k-tile fragments
            const __bf16* kp = kg_bh + (size_t)(ut + 1) * 64 * 32;
            #pragma unroll
            for (int s = 0; s < 2; ++s)
                #pragma unroll
                for (int st = 0; st < 2; ++st)
                    kA[s][st] = *(const bf16x8*)(kp + (size_t)(s * 32 + l31) * 32 + st * 16 + hi * 8);
        }

        // ---- P = exp2(S); no max subtraction (bounded scores) ----
        float rs = 0.f;
        #pragma unroll
        for (int r = 0; r < 16; ++r) {
            float p = __builtin_amdgcn_exp2f(s0[r]);
            s0[r] = p; rs += p;
        }
        #pragma unroll
        for (int r = 0; r < 16; ++r) {
            float p = __builtin_amdgcn_exp2f(s1[r]);
            s1[r] = p; rs += p;
        }
        lsum += rs;

        // ---- P -> fp8 A-frags ----
        long pf0, pf1, pf2, pf3;
        MK8FRAG(pf0, s0, 0);
        MK8FRAG(pf1, s0, 8);
        MK8FRAG(pf2, s1, 0);
        MK8FRAG(pf3, s1, 8);

        // ---- PV (fp8): acc[n] += P[q][u16] * x[u16][d-tile n] ----
        __builtin_amdgcn_s_setprio(1);
        #pragma unroll
        for (int kk = 0; kk < 4; ++kk) {
            const long pa = (kk == 0) ? pf0 : (kk == 1) ? pf1 : (kk == 2) ? pf2 : pf3;
            #pragma unroll
            for (int n = 0; n < 8; ++n) {
                const long xb = *(const long*)(xcur + (n * 32 + l31) * 72 + kk * 16 + hi * 8);
                acc[n] = MFMA8(pa, xb, acc[n]);
            }
        }
        __builtin_amdgcn_s_setprio(0);

        // ---- write staged tile (compiler inserts vmcnt wait here) ----
        {
            unsigned char* dp = xnxt + srow * 72 + soff;
            union { uint4 v; unsigned long long q[2]; } ua, ub;
            ua.v = la; ub.v = lb;
            ((unsigned long long*)dp)[0] = ua.q[0];
            ((unsigned long long*)dp)[1] = ua.q[1];
            ((unsigned long long*)(dp + 16))[0] = ub.q[0];
            ((unsigned long long*)(dp + 16))[1] = ub.q[1];
        }
        __syncthreads();
    }

    // ---- epilogue: combine lsum across lane halves, broadcast 1/lsum ----
    lsum += __shfl_xor(lsum, 32);
    const float linv = 1.0f / lsum;
    if (!hi) scale_w[l31] = linv;
    f32x4 iv[4];
    #pragma unroll
    for (int q4 = 0; q4 < 4; ++q4)
        iv[q4] = *(const f32x4*)&scale_w[q4 * 8 + hi * 4];
    #pragma unroll
    for (int n = 0; n < 8; ++n) {
        #pragma unroll
        for (int r = 0; r < 16; ++r) {
            int t = t0 + w * 32 + (r & 3) + 8 * (r >> 2) + 4 * hi;
            int d = n * 32 + l31;
            ctx[((size_t)(b * 4096 + t) * 8 + h) * 256 + d] =
                (__bf16)(acc[n][r] * iv[r >> 2][r & 3]);
        }
    }
}

// ---------------------------------------------------------------------------
// gemm_out (round-8): out[bt][e] = sum_k ctx[bt][k] * VOT[e][k].
// block = 64 m-rows x 128 e (4 waves; wave = 2 m-tiles x 32 e).
// ---------------------------------------------------------------------------
__global__ __launch_bounds__(256) void gemm_out(const __bf16* __restrict__ ctx,
                                                const __bf16* __restrict__ vot,
                                                float* __restrict__ out) {
    const int bid = blockIdx.x;
    const int mt2 = bid >> 1;
    const int eh = bid & 1;
    const int w = threadIdx.x >> 6;
    const int l = threadIdx.x & 63;
    const int l31 = l & 31, hi = l >> 5;
    const size_t a0row = (size_t)(mt2 * 64 + l31) * 2048;
    const size_t a1row = (size_t)(mt2 * 64 + 32 + l31) * 2048;
    const size_t brow  = (size_t)(eh * 128 + w * 32 + l31) * 2048;
    f32x16 acc0 = zf16(), acc1 = zf16();
    #pragma unroll 4
    for (int kk = 0; kk < 128; ++kk) {
        bf16x8 bfr = *(const bf16x8*)(vot + brow + kk * 16 + hi * 8);
        bf16x8 a0  = *(const bf16x8*)(ctx + a0row + kk * 16 + hi * 8);
        bf16x8 a1  = *(const bf16x8*)(ctx + a1row + kk * 16 + hi * 8);
        acc0 = MFMA32(a0, bfr, acc0);
        acc1 = MFMA32(a1, bfr, acc1);
    }
    const int e = eh * 128 + w * 32 + l31;
    #pragma unroll
    for (int r = 0; r < 16; ++r) {
        int crow = (r & 3) + 8 * (r >> 2) + 4 * hi;
        out[(size_t)(mt2 * 64 + crow) * 256 + e]      = acc0[r];
        out[(size_t)(mt2 * 64 + 32 + crow) * 256 + e] = acc1[r];
    }
}

// ---------------------------------------------------------------------------
extern "C" void kernel_launch(void* const* d_in, const int* in_sizes, int n_in,
                              void* d_out, int out_size, void* d_ws, size_t ws_size,
                              hipStream_t stream) {
    const float* x  = (const float*)d_in[0];  // [2][4096][256]
    const float* Qw = (const float*)d_in[1];  // [8][32][256]
    const float* Kw = (const float*)d_in[2];  // [8][32][256]
    const float* VO = (const float*)d_in[3];  // [8][256][256]
    float* out = (float*)d_out;               // [2][4096][256]

    char* ws = (char*)d_ws;
    unsigned char* x8 = (unsigned char*)(ws);              // 2 MB  [2][256][4096] fp8
    __bf16* xrow = (__bf16*)(ws + ((size_t)4 << 20));      // 4 MB  [2][4096][256]
    __bf16* qb   = (__bf16*)(ws + ((size_t)8 << 20));      // 4 MB  [2][8][4096][32]
    __bf16* kb   = (__bf16*)(ws + ((size_t)12 << 20));     // 4 MB
    __bf16* wb   = (__bf16*)(ws + ((size_t)16 << 20));     // 256 KB [2][8][32][256]
    __bf16* vot  = (__bf16*)(ws + ((size_t)17 << 20));     // 1 MB  [256][2048]
    __bf16* ctx  = (__bf16*)(ws + ((size_t)18 << 20));     // 32 MB [2][4096][8][256]

    prep<<<896, 256, 0, stream>>>(x, Qw, Kw, VO, x8, xrow, wb, vot);
    proj_kernel<<<128, 256, 0, stream>>>(xrow, wb, qb, kb);
    attn_kernel<<<256, 512, 0, stream>>>(qb, kb, x8, ctx);
    gemm_out<<<256, 256, 0, stream>>>(ctx, vot, out);
}